// Round 3
// baseline (12918.108 us; speedup 1.0000x reference)
//
#include <hip/hip_runtime.h>

// ---------------------------------------------------------------------------
// mLSTM epitope/antigen model, MI355X fp16-MFMA version, round 3.
//
// R3 changes vs R2 (8.49 ms):
//  - NO LDS in the GEMM kernels. Each wave loads its MFMA fragments directly
//    global->VGPR (half8 per lane, 64B-aligned rows). The LDS-DMA path
//    (global_load_lds + ds_read) provokes compiler-inserted vmcnt(0) drains
//    every iter; plain register loads get precise fine-grained vmcnt.
//  - 3-buffer rotating fragment prefetch (distance 2) in a fully-unrolled
//    K-loop -> compiler emits AITER-style interleaved MFMA/load with
//    vmcnt(N), never a full drain.
//  - Full-chip tiling: stepB wave = 32 rows x (16 cols x 4 gates),
//    238/476 blocks x 4 waves; stepA wave = 32x32, 120/240 blocks.
//    4 waves of a block share B-fragment addresses -> L1 reuse.
// ---------------------------------------------------------------------------

typedef _Float16 f16;
typedef _Float16 half8 __attribute__((ext_vector_type(8)));
typedef float f32x4 __attribute__((ext_vector_type(4)));

#define H_    1900
#define HP    1920   // padded hidden
#define KB    1952   // stepB K: 1920 + 10 (x-emb) + 1 (bias) + pad (61*32)
#define NR    512
#define NB_   256
#define TT    153
#define TE    25
#define EMB_  10
#define FCK   3840
#define FCN   384

__device__ __forceinline__ float sigm(float x) {
  float p = __expf(-fabsf(x));
  float r = 1.f / (1.f + p);
  return x >= 0.f ? r : 1.f - r;
}
__device__ __forceinline__ float tanh_(float x) {
  float p = __expf(-2.f * fabsf(x));
  float r = (1.f - p) / (1.f + p);
  return x >= 0.f ? r : -r;
}

// ---------------- prep kernels ----------------

__global__ void k_norms(const float* __restrict__ wh, const float* __restrict__ wx,
                        const float* __restrict__ wmh, const float* __restrict__ wmx,
                        const float* __restrict__ gh, const float* __restrict__ gx,
                        const float* __restrict__ gmh, const float* __restrict__ gmx,
                        float* __restrict__ inv_wh, float* __restrict__ inv_wx,
                        float* __restrict__ inv_wmh, float* __restrict__ inv_wmx) {
  int tid = blockIdx.x * 256 + threadIdx.x;
  if (tid < 7600) {
    float s = 0.f;
    for (int k = 0; k < H_; k++) { float v = wh[(size_t)k * 7600 + tid]; s += v * v; }
    inv_wh[tid] = gh[tid] * rsqrtf(fmaxf(s, 1e-12f));
  } else if (tid < 15200) {
    int n = tid - 7600; float s = 0.f;
    for (int e = 0; e < EMB_; e++) { float v = wx[(size_t)e * 7600 + n]; s += v * v; }
    inv_wx[n] = gx[n] * rsqrtf(fmaxf(s, 1e-12f));
  } else if (tid < 17100) {
    int n = tid - 15200; float s = 0.f;
    for (int k = 0; k < H_; k++) { float v = wmh[(size_t)k * H_ + n]; s += v * v; }
    inv_wmh[n] = gmh[n] * rsqrtf(fmaxf(s, 1e-12f));
  } else if (tid < 19000) {
    int n = tid - 17100; float s = 0.f;
    for (int e = 0; e < EMB_; e++) { float v = wmx[(size_t)e * H_ + n]; s += v * v; }
    inv_wmx[n] = gmx[n] * rsqrtf(fmaxf(s, 1e-12f));
  }
}

// WmhT[n][k] = wmh[k][n]*inv[n], fp16, [1920][1920]
__global__ void k_wmhT(const float* __restrict__ wmh, const float* __restrict__ inv,
                       f16* __restrict__ WmhT) {
  __shared__ float tl[32][33];
  int tx = threadIdx.x, ty = threadIdx.y;
  int kb = blockIdx.y * 32, nb = blockIdx.x * 32;
  #pragma unroll
  for (int i = 0; i < 4; i++) {
    int k = kb + ty + i * 8, n = nb + tx;
    tl[ty + i * 8][tx] = (k < H_ && n < H_) ? wmh[(size_t)k * H_ + n] * inv[n] : 0.f;
  }
  __syncthreads();
  #pragma unroll
  for (int i = 0; i < 4; i++) {
    int n = nb + ty + i * 8, k = kb + tx;
    WmhT[(size_t)n * HP + k] = (f16)tl[tx][ty + i * 8];
  }
}

// WhT[g][n][k]: k<1900 -> wh_n; k in [1920,1930) -> wx_n; k==1930 -> b
__global__ void k_whT(const float* __restrict__ wh, const float* __restrict__ wx,
                      const float* __restrict__ bias,
                      const float* __restrict__ inv_wh, const float* __restrict__ inv_wx,
                      f16* __restrict__ WhT) {
  __shared__ float tl[32][33];
  int tx = threadIdx.x, ty = threadIdx.y;
  int g = blockIdx.z;
  int kb = blockIdx.y * 32, nb = blockIdx.x * 32;
  #pragma unroll
  for (int i = 0; i < 4; i++) {
    int k = kb + ty + i * 8, n = nb + tx;
    float v = 0.f;
    if (n < H_) {
      int col = g * H_ + n;
      if (k < H_)                        v = wh[(size_t)k * 7600 + col] * inv_wh[col];
      else if (k >= HP && k < HP + EMB_) v = wx[(size_t)(k - HP) * 7600 + col] * inv_wx[col];
      else if (k == HP + EMB_)           v = bias[col];
    }
    tl[ty + i * 8][tx] = v;
  }
  __syncthreads();
  #pragma unroll
  for (int i = 0; i < 4; i++) {
    int n = nb + ty + i * 8, k = kb + tx;
    WhT[((size_t)g * HP + n) * KB + k] = (f16)tl[tx][ty + i * 8];
  }
}

// wmxT[n][32]: k<10 -> wmx_n[k][n], else 0  (B operand of the xm-MFMA)
__global__ void k_wmxT(const float* __restrict__ wmx, const float* __restrict__ inv_wmx,
                       f16* __restrict__ wmxT) {
  int i = blockIdx.x * 256 + threadIdx.x;
  if (i >= HP * 32) return;
  int n = i >> 5, k = i & 31;
  float v = (k < EMB_ && n < H_) ? wmx[(size_t)k * H_ + n] * inv_wmx[n] : 0.f;
  wmxT[i] = (f16)v;
}

__global__ void k_lens(const int* __restrict__ ex, const int* __restrict__ lx,
                       const int* __restrict__ rx, int* __restrict__ sel) {
  int s = threadIdx.x;
  int el = 0; for (int i = 0; i < 25; i++) el += (ex[s * 25 + i] != 26);
  int ll = 0; for (int i = 0; i < 64; i++) ll += (lx[s * 64 + i] != 26);
  int rl = 0; for (int i = 0; i < 64; i++) rl += (rx[s * 64 + i] != 26);
  ll = ll < 1 ? 1 : ll;  rl = rl < 1 ? 1 : rl;
  int tl = el + ll + rl;
  int ti = tl - 1; ti = ti < 0 ? 0 : (ti > 152 ? 152 : ti);
  int ei = el - 1; ei = ei < 0 ? 0 : (ei > 24 ? 24 : ei);
  sel[s] = ti; sel[256 + s] = ei;
}

__global__ void k_init(f16* __restrict__ h0, f16* __restrict__ h1, float* __restrict__ c) {
  int i = blockIdx.x * 256 + threadIdx.x;
  if (i < NR * HP) { h0[i] = (f16)0.f; h1[i] = (f16)0.f; c[i] = 0.f; }
}

// xe16[t][row][32]: cols 0..9 = embed[token], col 10 = 1.0 (bias), rest 0
__global__ void k_xe16(const int* __restrict__ totx, const int* __restrict__ epix,
                       const float* __restrict__ embed, f16* __restrict__ xe16) {
  int i = blockIdx.x * blockDim.x + threadIdx.x;
  if (i >= TT * NR) return;
  int t = i / NR, r = i % NR;
  int tok = -1;
  if (r < 256) tok = totx[r * TT + t];
  else if (t < TE) tok = epix[(r - 256) * TE + t];
  f16* o = xe16 + (size_t)i * 32;
  #pragma unroll
  for (int e = 0; e < EMB_; e++) o[e] = (f16)(tok >= 0 ? embed[tok * EMB_ + e] : 0.f);
  o[10] = (f16)1.f;
  #pragma unroll
  for (int e = 11; e < 32; e++) o[e] = (f16)0.f;
}

// ---------------- recurrence kernels (register-direct, no LDS) ----------------

// Phase A: wave = 32 rows x 32 cols of hm = h @ WmhT (K=1920, 60 iters),
// m = (xe16 @ wmxT) ⊙ hm via a matching xm MFMA. Block = 4 row-waves, 1 col.
__global__ __launch_bounds__(256)
void k_stepA(const f16* __restrict__ h, const f16* __restrict__ WmhT,
             const f16* __restrict__ xe16_t, const f16* __restrict__ wmxT,
             f16* __restrict__ m) {
  const int lane = threadIdx.x & 63, wid = threadIdx.x >> 6;
  const int col = blockIdx.x % 60, rgrp = blockIdx.x / 60;
  const int r0 = (rgrp * 4 + wid) * 32;
  const int c0 = col * 32;
  const int l16 = lane & 15, l4 = lane >> 4;

  const f16* Abase = h    + (size_t)(r0 + l16) * HP + l4 * 8;  // + rb*16*HP + k
  const f16* Bbase = WmhT + (size_t)(c0 + l16) * HP + l4 * 8;  // + cb*16*HP + k

  // xm = xe16 @ wmxT (single K=32 MFMA per frag pair), same C-layout as hm
  f32x4 xm[2][2];
  {
    half8 xa[2], xb[2];
    #pragma unroll
    for (int rb = 0; rb < 2; rb++)
      xa[rb] = *(const half8*)(xe16_t + (size_t)(r0 + rb * 16 + l16) * 32 + l4 * 8);
    #pragma unroll
    for (int cb = 0; cb < 2; cb++)
      xb[cb] = *(const half8*)(wmxT + (size_t)(c0 + cb * 16 + l16) * 32 + l4 * 8);
    #pragma unroll
    for (int rb = 0; rb < 2; rb++)
      #pragma unroll
      for (int cb = 0; cb < 2; cb++) {
        f32x4 z = {0.f, 0.f, 0.f, 0.f};
        xm[rb][cb] = __builtin_amdgcn_mfma_f32_16x16x32_f16(xa[rb], xb[cb], z, 0, 0, 0);
      }
  }

  half8 fa[3][2], fb[3][2];
  auto loadA = [&](int buf, int kb) {
    #pragma unroll
    for (int rb = 0; rb < 2; rb++)
      fa[buf][rb] = *(const half8*)(Abase + (size_t)rb * 16 * HP + kb * 32);
  };
  auto loadB = [&](int buf, int kb) {
    #pragma unroll
    for (int cb = 0; cb < 2; cb++)
      fb[buf][cb] = *(const half8*)(Bbase + (size_t)cb * 16 * HP + kb * 32);
  };
  loadA(0, 0); loadB(0, 0);
  loadA(1, 1); loadB(1, 1);

  f32x4 acc[2][2];
  #pragma unroll
  for (int a = 0; a < 2; a++)
    #pragma unroll
    for (int b = 0; b < 2; b++) { f32x4 z = {0.f, 0.f, 0.f, 0.f}; acc[a][b] = z; }

  #pragma unroll
  for (int kb = 0; kb < 60; kb++) {
    if (kb + 2 < 60) { loadA((kb + 2) % 3, kb + 2); loadB((kb + 2) % 3, kb + 2); }
    const int cu = kb % 3;
    #pragma unroll
    for (int rb = 0; rb < 2; rb++)
      #pragma unroll
      for (int cb = 0; cb < 2; cb++)
        acc[rb][cb] = __builtin_amdgcn_mfma_f32_16x16x32_f16(fa[cu][rb], fb[cu][cb], acc[rb][cb], 0, 0, 0);
  }

  const int q4 = lane >> 4, c16 = lane & 15;
  #pragma unroll
  for (int rb = 0; rb < 2; rb++)
    #pragma unroll
    for (int cb = 0; cb < 2; cb++)
      #pragma unroll
      for (int q = 0; q < 4; q++) {
        int row = r0 + rb * 16 + q4 * 4 + q;
        int cc  = c0 + cb * 16 + c16;
        m[(size_t)row * KB + cc] = (f16)(acc[rb][cb][q] * xm[rb][cb][q]);
      }
  if (col == 0) {  // K-extension tail (cols 1920..1951) = xe16 row
    int row = r0 + (lane >> 1);
    int base = (lane & 1) * 16;
    const f16* src = xe16_t + (size_t)row * 32 + base;
    f16* dst = m + (size_t)row * KB + HP + base;
    *(half8*)dst       = *(const half8*)src;
    *(half8*)(dst + 8) = *(const half8*)(src + 8);
  }
}

// Phase B: wave = 32 rows x (16 cols x 4 gates) of z = m @ WhT (K=1952, 61
// iters) + fused gate update. Block = 4 row-waves sharing one col-group.
__global__ __launch_bounds__(256)
void k_stepB(const f16* __restrict__ m, const f16* __restrict__ WhT,
             float* __restrict__ c, f16* __restrict__ hout,
             float* __restrict__ selH, const int* __restrict__ sel, int t) {
  const int lane = threadIdx.x & 63, wid = threadIdx.x >> 6;
  const int colg = blockIdx.x % 119, rgrp = blockIdx.x / 119;
  const int r0 = (rgrp * 4 + wid) * 32;
  const int c0 = colg * 16;
  const int l16 = lane & 15, l4 = lane >> 4;

  const f16* Abase = m   + (size_t)(r0 + l16) * KB + l4 * 8;  // + rb*16*KB + k
  const f16* Bbase = WhT + (size_t)(c0 + l16) * KB + l4 * 8;  // + gg*HP*KB + k

  half8 fa[3][2], fb[3][4];
  auto loadA = [&](int buf, int kb) {
    #pragma unroll
    for (int rb = 0; rb < 2; rb++)
      fa[buf][rb] = *(const half8*)(Abase + (size_t)rb * 16 * KB + kb * 32);
  };
  auto loadB = [&](int buf, int kb) {
    #pragma unroll
    for (int gg = 0; gg < 4; gg++)
      fb[buf][gg] = *(const half8*)(Bbase + (size_t)gg * HP * KB + kb * 32);
  };
  loadA(0, 0); loadB(0, 0);
  loadA(1, 1); loadB(1, 1);

  f32x4 acc[2][4];  // [row-frag][gate]
  #pragma unroll
  for (int a = 0; a < 2; a++)
    #pragma unroll
    for (int b = 0; b < 4; b++) { f32x4 z = {0.f, 0.f, 0.f, 0.f}; acc[a][b] = z; }

  #pragma unroll
  for (int kb = 0; kb < 61; kb++) {
    if (kb + 2 < 61) { loadA((kb + 2) % 3, kb + 2); loadB((kb + 2) % 3, kb + 2); }
    const int cu = kb % 3;
    #pragma unroll
    for (int rb = 0; rb < 2; rb++)
      #pragma unroll
      for (int gg = 0; gg < 4; gg++)
        acc[rb][gg] = __builtin_amdgcn_mfma_f32_16x16x32_f16(fa[cu][rb], fb[cu][gg], acc[rb][gg], 0, 0, 0);
  }

  const int q4 = lane >> 4, c16 = lane & 15;
  const int j = c0 + c16;
  const bool valid = j < H_;
  #pragma unroll
  for (int rb = 0; rb < 2; rb++)
    #pragma unroll
    for (int q = 0; q < 4; q++) {
      int row = r0 + rb * 16 + q4 * 4 + q;
      size_t idx = (size_t)row * HP + j;
      if (valid) {
        float cold = c[idx];
        float iz = acc[rb][0][q], fz = acc[rb][1][q];
        float oz = acc[rb][2][q], uz = acc[rb][3][q];
        float cn = sigm(fz) * cold + sigm(iz) * tanh_(uz);
        float hv = sigm(oz) * tanh_(cn);
        c[idx] = cn;
        hout[idx] = (f16)hv;
        if (t == sel[row]) selH[idx] = hv;
      } else {
        c[idx] = 0.f; hout[idx] = (f16)0.f;
      }
    }
}

// ---------------- classifier ----------------

__global__ void k_xq(const float* __restrict__ selH, const float* __restrict__ g1,
                     const float* __restrict__ be1, const float* __restrict__ mu1,
                     const float* __restrict__ var1, f16* __restrict__ xq) {
  int i = blockIdx.x * 256 + threadIdx.x;
  if (i >= 256 * FCK) return;
  int s = i / FCK, k = i % FCK;
  float v = 0.f;
  if (k < H_)          v = selH[(size_t)s * HP + k];
  else if (k < 2 * H_) v = selH[(size_t)(256 + s) * HP + (k - H_)];
  float lr = v < 0.f ? 0.3f * v : v;
  float q = 0.f;
  if (k < 2 * H_) q = (lr - mu1[k]) * rsqrtf(var1[k] + 1e-3f) * g1[k] + be1[k];
  xq[i] = (f16)q;
}

__global__ void k_w1t(const float* __restrict__ W1, f16* __restrict__ W1T) {
  int i = blockIdx.x * 256 + threadIdx.x;
  if (i >= FCN * FCK) return;
  int cidx = i / FCK, k = i % FCK;
  W1T[i] = (f16)((cidx < 380 && k < 2 * H_) ? W1[(size_t)k * 380 + cidx] : 0.f);
}

// fc1: register-direct, wave = 64x64, block = 4 row-waves, K=3840 (120 iters)
__global__ __launch_bounds__(256)
void k_fc1(const f16* __restrict__ xq, const f16* __restrict__ W1T,
           const float* __restrict__ b1, float* __restrict__ z1) {
  const int lane = threadIdx.x & 63, wid = threadIdx.x >> 6;
  const int r0 = wid * 64, c0 = blockIdx.x * 64;
  const int l16 = lane & 15, l4 = lane >> 4;

  const f16* Abase = xq  + (size_t)(r0 + l16) * FCK + l4 * 8;
  const f16* Bbase = W1T + (size_t)(c0 + l16) * FCK + l4 * 8;

  half8 fa[3][4], fb[3][4];
  auto loadA = [&](int buf, int kb) {
    #pragma unroll
    for (int rb = 0; rb < 4; rb++)
      fa[buf][rb] = *(const half8*)(Abase + (size_t)rb * 16 * FCK + kb * 32);
  };
  auto loadB = [&](int buf, int kb) {
    #pragma unroll
    for (int cb = 0; cb < 4; cb++)
      fb[buf][cb] = *(const half8*)(Bbase + (size_t)cb * 16 * FCK + kb * 32);
  };
  loadA(0, 0); loadB(0, 0);
  loadA(1, 1); loadB(1, 1);

  f32x4 acc[4][4];
  #pragma unroll
  for (int a = 0; a < 4; a++)
    #pragma unroll
    for (int b = 0; b < 4; b++) { f32x4 z = {0.f, 0.f, 0.f, 0.f}; acc[a][b] = z; }

  #pragma unroll 3
  for (int kb = 0; kb < 120; kb++) {
    if (kb + 2 < 120) { loadA((kb + 2) % 3, kb + 2); loadB((kb + 2) % 3, kb + 2); }
    const int cu = kb % 3;
    #pragma unroll
    for (int rb = 0; rb < 4; rb++)
      #pragma unroll
      for (int cb = 0; cb < 4; cb++)
        acc[rb][cb] = __builtin_amdgcn_mfma_f32_16x16x32_f16(fa[cu][rb], fb[cu][cb], acc[rb][cb], 0, 0, 0);
  }

  const int q4 = lane >> 4, c16 = lane & 15;
  #pragma unroll
  for (int rb = 0; rb < 4; rb++)
    #pragma unroll
    for (int cb = 0; cb < 4; cb++)
      #pragma unroll
      for (int q = 0; q < 4; q++) {
        int rl = r0 + rb * 16 + q4 * 4 + q;
        int col = c0 + cb * 16 + c16;
        float bias = (col < 380) ? b1[col] : 0.f;
        z1[(size_t)rl * FCN + col] = acc[rb][cb][q] + bias;
      }
}

__global__ void k_fc2(const float* __restrict__ z1, const float* __restrict__ g2,
                      const float* __restrict__ be2, const float* __restrict__ mu2,
                      const float* __restrict__ var2, const float* __restrict__ W2,
                      const float* __restrict__ b2, float* __restrict__ out) {
  int s = threadIdx.x;
  float a = 0.f;
  for (int jj = 0; jj < 380; jj++) {
    float v = z1[(size_t)s * FCN + jj];
    float lr = v < 0.f ? 0.3f * v : v;
    float q = (lr - mu2[jj]) * rsqrtf(var2[jj] + 1e-3f) * g2[jj] + be2[jj];
    a += q * W2[jj];
  }
  out[s] = a + b2[0];
}

// ---------------- host ----------------

extern "C" void kernel_launch(void* const* d_in, const int* in_sizes, int n_in,
                              void* d_out, int out_size, void* d_ws, size_t ws_size,
                              hipStream_t stream) {
  const int*   epix  = (const int*)d_in[0];
  const int*   lx    = (const int*)d_in[1];
  const int*   rx    = (const int*)d_in[2];
  const int*   totx  = (const int*)d_in[3];
  const float* embed = (const float*)d_in[4];
  const float* wx    = (const float*)d_in[5];
  const float* wh    = (const float*)d_in[6];
  const float* wmx   = (const float*)d_in[7];
  const float* wmh   = (const float*)d_in[8];
  const float* bb    = (const float*)d_in[9];
  const float* gx    = (const float*)d_in[10];
  const float* gh    = (const float*)d_in[11];
  const float* gmx   = (const float*)d_in[12];
  const float* gmh   = (const float*)d_in[13];
  const float* bn1g  = (const float*)d_in[14];
  const float* bn1b  = (const float*)d_in[15];
  const float* bn1m  = (const float*)d_in[16];
  const float* bn1v  = (const float*)d_in[17];
  const float* W1    = (const float*)d_in[18];
  const float* b1    = (const float*)d_in[19];
  const float* bn2g  = (const float*)d_in[20];
  const float* bn2b  = (const float*)d_in[21];
  const float* bn2m  = (const float*)d_in[22];
  const float* bn2v  = (const float*)d_in[23];
  const float* W2    = (const float*)d_in[24];
  const float* b2v   = (const float*)d_in[25];

  char* base = (char*)d_ws;
  size_t off = 0;
  auto alloc = [&](size_t n) { char* p = base + off; off = (off + n + 255) & ~(size_t)255; return p; };

  f16*   WmhT   = (f16*)  alloc((size_t)HP * HP * 2);
  f16*   WhT    = (f16*)  alloc((size_t)4 * HP * KB * 2);
  f16*   wmxT   = (f16*)  alloc((size_t)HP * 32 * 2);
  f16*   xe16   = (f16*)  alloc((size_t)TT * NR * 32 * 2);
  f16*   h0     = (f16*)  alloc((size_t)NR * HP * 2);
  f16*   h1     = (f16*)  alloc((size_t)NR * HP * 2);
  f16*   mbuf   = (f16*)  alloc((size_t)NR * KB * 2);
  float* cst    = (float*)alloc((size_t)NR * HP * 4);
  float* selH   = (float*)alloc((size_t)NR * HP * 4);
  int*   sel    = (int*)  alloc((size_t)NR * 4);
  float* inv_wh = (float*)alloc(7600 * 4);
  float* inv_wx = (float*)alloc(7600 * 4);
  float* inv_wmh= (float*)alloc(1900 * 4);
  float* inv_wmx= (float*)alloc(1900 * 4);
  f16*   xq     = (f16*)  alloc((size_t)256 * FCK * 2);
  f16*   W1T    = (f16*)  alloc((size_t)FCN * FCK * 2);
  float* z1     = (float*)alloc((size_t)256 * FCN * 4);
  (void)in_sizes; (void)n_in; (void)out_size; (void)ws_size;

  hipLaunchKernelGGL(k_norms, dim3(75), dim3(256), 0, stream,
                     wh, wx, wmh, wmx, gh, gx, gmh, gmx, inv_wh, inv_wx, inv_wmh, inv_wmx);
  hipLaunchKernelGGL(k_wmhT, dim3(60, 60), dim3(32, 8), 0, stream, wmh, inv_wmh, WmhT);
  hipLaunchKernelGGL(k_whT, dim3(60, 61, 4), dim3(32, 8), 0, stream,
                     wh, wx, bb, inv_wh, inv_wx, WhT);
  hipLaunchKernelGGL(k_wmxT, dim3((HP * 32 + 255) / 256), dim3(256), 0, stream,
                     wmx, inv_wmx, wmxT);
  hipLaunchKernelGGL(k_lens, dim3(1), dim3(256), 0, stream, epix, lx, rx, sel);
  hipLaunchKernelGGL(k_init, dim3((NR * HP + 255) / 256), dim3(256), 0, stream, h0, h1, cst);
  hipLaunchKernelGGL(k_xe16, dim3((TT * NR + 255) / 256), dim3(256), 0, stream,
                     totx, epix, embed, xe16);

  for (int t = 0; t < TT; t++) {
    int Mt = (t < TE) ? NR : NB_;
    const f16* hin = (t & 1) ? h1 : h0;
    f16*       ho  = (t & 1) ? h0 : h1;
    int rg = Mt / 128;  // row-groups of 128 (4 waves x 32 rows)
    hipLaunchKernelGGL(k_stepA, dim3(60 * rg), dim3(256), 0, stream,
                       hin, WmhT, xe16 + (size_t)t * NR * 32, wmxT, mbuf);
    hipLaunchKernelGGL(k_stepB, dim3(119 * rg), dim3(256), 0, stream,
                       mbuf, WhT, cst, ho, selH, sel, t);
  }

  hipLaunchKernelGGL(k_xq, dim3((256 * FCK + 255) / 256), dim3(256), 0, stream,
                     selH, bn1g, bn1b, bn1m, bn1v, xq);
  hipLaunchKernelGGL(k_w1t, dim3((FCN * FCK + 255) / 256), dim3(256), 0, stream, W1, W1T);
  hipLaunchKernelGGL(k_fc1, dim3(6), dim3(256), 0, stream, xq, W1T, b1, z1);
  hipLaunchKernelGGL(k_fc2, dim3(1), dim3(256), 0, stream,
                     z1, bn2g, bn2b, bn2m, bn2v, W2, b2v, (float*)d_out);
}